// Round 1
// baseline (400.903 us; speedup 1.0000x reference)
//
#include <hip/hip_runtime.h>
#include <stdint.h>

// ---------------------------------------------------------------------------
// SelfAttention: out[b,n,d] = ( softmax( (X^T Wk)(X^T Wq)^T / 32 ) (X^T Wv) )^T
// B=16, N=D=1024.  All five matmuls are 1024^3, run as the verified m97-style
// gemm_bt (C[m,n] = sum_k A[m,k]*B[n,k], K contiguous in both operands).
// ---------------------------------------------------------------------------

typedef __bf16 bf16x8_t __attribute__((ext_vector_type(8)));
typedef float  f32x4_t  __attribute__((ext_vector_type(4)));

typedef __attribute__((address_space(3))) uint32_t as3_u32;
typedef __attribute__((address_space(1))) uint32_t as1_u32;

// async global->LDS, 16 B per lane.  HW semantics: wave-uniform LDS base +
// lane*16; we pass base+lane*16 per-lane which is consistent either way.
__device__ __forceinline__ void async_copy16(const void* g, const void* l) {
  __builtin_amdgcn_global_load_lds((const as1_u32*)(uintptr_t)g,
                                   (as3_u32*)(uint32_t)(uintptr_t)l,
                                   16, 0, 0);
}

__device__ __forceinline__ uint16_t f2bf(float f) {  // RNE
  uint32_t x = __float_as_uint(f);
  return (uint16_t)((x + 0x7fffu + ((x >> 16) & 1u)) >> 16);
}
__device__ __forceinline__ float bf2f(uint16_t b) {
  return __uint_as_float(((uint32_t)b) << 16);
}

// Swizzled LDS byte offset for (row m, 16B chunk c) in a [128][32]-bf16 tile
// (row pitch 64 B).  chunk' = c ^ ((m>>1)&3) spreads the b128 fragment reads
// to ~2-way bank aliasing (free).  Staging inverts the same mapping.
#define LDS_CH(m, c) (((m) << 6) + ((((c) ^ (((m) >> 1) & 3))) << 4))

// C[m,n] = alpha * sum_k A[m,k] * B[n,k]   (A: M x K row-major, B: N x K
// row-major, C: M x ldc row-major).  Tile 128x128, BK=32, 256 threads.
template <bool OUT_F32>
__global__ __launch_bounds__(256, 2)
void gemm_bt(const uint16_t* __restrict__ A, const uint16_t* __restrict__ B,
             void* __restrict__ Cv, int K, int ldc,
             size_t sA, size_t sB, size_t sC, float alpha)
{
  __shared__ __align__(16) char smem[16384];
  char* As = smem;          // 128 x 32 bf16 = 8192 B
  char* Bs = smem + 8192;

  const int z = blockIdx.z;
  A += (size_t)z * sA;
  B += (size_t)z * sB;

  const int t    = threadIdx.x;
  const int lane = t & 63;
  const int w    = t >> 6;         // wave 0..3
  const int q    = lane >> 4;      // 0..3
  const int r16  = lane & 15;
  const int wm   = (w >> 1) << 6;  // wave quadrant row base (0/64)
  const int wn   = (w & 1) << 6;

  const int bm0 = blockIdx.y << 7;
  const int bn0 = blockIdx.x << 7;

  f32x4_t acc[4][4];
#pragma unroll
  for (int i = 0; i < 4; i++)
#pragma unroll
    for (int j = 0; j < 4; j++) acc[i][j] = (f32x4_t){0.f, 0.f, 0.f, 0.f};

  const int oa0 = (w << 11) + (lane << 4);  // wave w covers LDS [2048w,2048w+2048)

  for (int k0 = 0; k0 < K; k0 += 32) {
    // ---- stage A,B tiles (global -> LDS, 16 B/lane, 2 issues/operand) ----
#pragma unroll
    for (int i = 0; i < 2; i++) {
      const int o  = oa0 + (i << 10);
      const int mm = o >> 6;            // tile row (64 B rows)
      const int cp = (o >> 4) & 3;      // LDS chunk slot
      const int c  = cp ^ ((mm >> 1) & 3);  // logical k-chunk held there
      const size_t gofs = (size_t)(bm0 + mm) * K + (size_t)(k0 + (c << 3));
      async_copy16(A + gofs, As + o);
      const size_t gofsb = (size_t)(bn0 + mm) * K + (size_t)(k0 + (c << 3));
      async_copy16(B + gofsb, Bs + o);
    }
    __syncthreads();   // compiler emits s_waitcnt vmcnt(0) before barrier

    // ---- fragments: A[m=lane&15][k=q*8+j], B[n=lane&15][k=q*8+j] ----
    bf16x8_t af[4], bfr[4];
#pragma unroll
    for (int mi = 0; mi < 4; mi++) {
      const int m = wm + (mi << 4) + r16;
      af[mi] = *(const bf16x8_t*)(As + LDS_CH(m, q));
    }
#pragma unroll
    for (int ni = 0; ni < 4; ni++) {
      const int n = wn + (ni << 4) + r16;
      bfr[ni] = *(const bf16x8_t*)(Bs + LDS_CH(n, q));
    }
#pragma unroll
    for (int mi = 0; mi < 4; mi++)
#pragma unroll
      for (int ni = 0; ni < 4; ni++)
        acc[mi][ni] = __builtin_amdgcn_mfma_f32_16x16x32_bf16(
            af[mi], bfr[ni], acc[mi][ni], 0, 0, 0);
    __syncthreads();
  }

  // ---- epilogue: C/D layout col=lane&15, row=q*4+r (verified m89/m91) ----
#pragma unroll
  for (int mi = 0; mi < 4; mi++) {
#pragma unroll
    for (int ni = 0; ni < 4; ni++) {
#pragma unroll
      for (int r = 0; r < 4; r++) {
        const int row = bm0 + wm + (mi << 4) + (q << 2) + r;
        const int col = bn0 + wn + (ni << 4) + r16;
        const float v = acc[mi][ni][r] * alpha;
        if (OUT_F32) {
          ((float*)Cv)[(size_t)z * sC + (size_t)row * ldc + col] = v;
        } else {
          ((uint16_t*)Cv)[(size_t)z * sC + (size_t)row * ldc + col] = f2bf(v);
        }
      }
    }
  }
}

// dst[c][r] = (bf16) src[r][c]; src: R x C fp32 row-major.  32x32 LDS tiles.
__global__ __launch_bounds__(256)
void transpose_cast(const float* __restrict__ src, uint16_t* __restrict__ dst,
                    int R, int Ccols, size_t sStride, size_t dStride)
{
  __shared__ float tile[32][33];
  const int z = blockIdx.z;
  src += (size_t)z * sStride;
  dst += (size_t)z * dStride;
  const int c0 = blockIdx.x << 5;
  const int r0 = blockIdx.y << 5;
  const int tx = threadIdx.x;   // 0..31
  const int ty = threadIdx.y;   // 0..7
#pragma unroll
  for (int i = 0; i < 32; i += 8)
    tile[ty + i][tx] = src[(size_t)(r0 + ty + i) * Ccols + (c0 + tx)];
  __syncthreads();
#pragma unroll
  for (int i = 0; i < 32; i += 8)
    dst[(size_t)(c0 + ty + i) * R + (r0 + tx)] = f2bf(tile[tx][ty + i]);
}

// row softmax over 1024 bf16 logits; one 256-thread block per row.
__global__ __launch_bounds__(256)
void softmax_rows(const uint16_t* __restrict__ in, uint16_t* __restrict__ out)
{
  const size_t row = blockIdx.x;
  const ushort4* p4 = (const ushort4*)(in + row * 1024);
  ushort4* o4 = (ushort4*)(out + row * 1024);
  const int t = threadIdx.x;
  const int lane = t & 63;
  const int wv = t >> 6;

  const ushort4 u = p4[t];
  float v0 = bf2f(u.x), v1 = bf2f(u.y), v2 = bf2f(u.z), v3 = bf2f(u.w);

  float m = fmaxf(fmaxf(v0, v1), fmaxf(v2, v3));
#pragma unroll
  for (int s = 32; s; s >>= 1) m = fmaxf(m, __shfl_xor(m, s, 64));
  __shared__ float red[8];
  if (lane == 0) red[wv] = m;
  __syncthreads();
  m = fmaxf(fmaxf(red[0], red[1]), fmaxf(red[2], red[3]));

  const float e0 = __expf(v0 - m), e1 = __expf(v1 - m);
  const float e2 = __expf(v2 - m), e3 = __expf(v3 - m);
  float s = e0 + e1 + e2 + e3;
#pragma unroll
  for (int sh = 32; sh; sh >>= 1) s += __shfl_xor(s, sh, 64);
  if (lane == 0) red[4 + wv] = s;
  __syncthreads();
  s = red[4] + red[5] + red[6] + red[7];

  const float inv = 1.0f / s;
  ushort4 r;
  r.x = f2bf(e0 * inv); r.y = f2bf(e1 * inv);
  r.z = f2bf(e2 * inv); r.w = f2bf(e3 * inv);
  o4[t] = r;
}

extern "C" void kernel_launch(void* const* d_in, const int* in_sizes, int n_in,
                              void* d_out, int out_size, void* d_ws, size_t ws_size,
                              hipStream_t stream)
{
  const float* x  = (const float*)d_in[0];
  const float* wk = (const float*)d_in[1];
  const float* wq = (const float*)d_in[2];
  const float* wv = (const float*)d_in[3];
  float* out = (float*)d_out;

  constexpr int BB = 16, N = 1024, D = 1024;
  constexpr size_t DN = (size_t)D * N;        // 1048576 elements

  // workspace layout (bytes)            size    lifetime
  // xT   @ 0                            32 MB   dead after G3 -> reused as kq
  // Wtk  @ 32M, Wtq @ 34M, Wtv @ 36M     6 MB
  // vk   @ 38M                          32 MB   dead after G4 -> reused as sm
  // vq   @ 70M                          32 MB
  // vvT  @ 102M                         32 MB   (total 134 MB)
  char* ws = (char*)d_ws;
  uint16_t* xT  = (uint16_t*)(ws);
  uint16_t* Wtk = (uint16_t*)(ws + (32ull << 20));
  uint16_t* Wtq = (uint16_t*)(ws + (34ull << 20));
  uint16_t* Wtv = (uint16_t*)(ws + (36ull << 20));
  uint16_t* vk  = (uint16_t*)(ws + (38ull << 20));
  uint16_t* vq  = (uint16_t*)(ws + (70ull << 20));
  uint16_t* vvT = (uint16_t*)(ws + (102ull << 20));
  uint16_t* kq  = xT;   // logits reuse xT
  uint16_t* sm  = vk;   // softmax output reuses vk

  const dim3 tb(32, 8);
  // xT[b][d][n] = x[b][n][d]
  transpose_cast<<<dim3(D / 32, N / 32, BB), tb, 0, stream>>>(x, xT, N, D, DN, DN);
  // Wt[k][n'] = w[n'][k]
  transpose_cast<<<dim3(N / 32, N / 32, 1), tb, 0, stream>>>(wk, Wtk, N, N, 0, 0);
  transpose_cast<<<dim3(N / 32, N / 32, 1), tb, 0, stream>>>(wq, Wtq, N, N, 0, 0);
  transpose_cast<<<dim3(N / 32, N / 32, 1), tb, 0, stream>>>(wv, Wtv, N, N, 0, 0);

  const dim3 gg(8, 8, BB);
  // vk[b][d][k] = sum_n xT[b][d][n] * Wtk[k][n]
  gemm_bt<false><<<gg, 256, 0, stream>>>(xT, Wtk, vk, 1024, 1024, DN, 0, DN, 1.0f);
  gemm_bt<false><<<gg, 256, 0, stream>>>(xT, Wtq, vq, 1024, 1024, DN, 0, DN, 1.0f);
  // vvT[b][n][d] = sum_n' Wtv[n][n'] * xT[b][d][n']   (= vv[b,d,n] transposed)
  gemm_bt<false><<<gg, 256, 0, stream>>>(Wtv, xT, vvT, 1024, 1024, 0, DN, DN, 1.0f);
  // kq[b][d][e] = (1/32) sum_n vk[b][d][n] * vq[b][e][n]
  gemm_bt<false><<<gg, 256, 0, stream>>>(vk, vq, kq, 1024, 1024, DN, DN, DN, 0.03125f);
  // sm = softmax(kq, rows of length 1024)
  softmax_rows<<<BB * D, 256, 0, stream>>>(kq, sm);
  // out[b][n][d] = sum_e vvT[b][n][e] * sm[b][d][e]
  gemm_bt<true><<<gg, 256, 0, stream>>>(vvT, sm, out, 1024, 1024, DN, DN, DN, 1.0f);
}

// Round 2
// 358.099 us; speedup vs baseline: 1.1195x; 1.1195x over previous
//
#include <hip/hip_runtime.h>
#include <stdint.h>

// ---------------------------------------------------------------------------
// SelfAttention: out[b,n,d] = ( softmax( (X^T Wk)(X^T Wq)^T / 32 ) (X^T Wv) )^T
// B=16, N=D=1024.  Five 1024^3 matmuls as m97-style gemm_bt
// (C[m,n] = sum_k A[m,k]*B[n,k], K contiguous in both operands).
//
// R2: XCD-aware tile swizzle.  1024 blocks dispatch round-robin over 8 XCDs
// (lid%8); slot lid/8 walks 2 full batches per XCD (x fastest, then y, then
// batch) so the 8 tiles sharing A-rows are temporally adjacent on ONE XCD's
// L2.  Target: FETCH_SIZE 154 MB -> ~60-80 MB per GEMM.
// ---------------------------------------------------------------------------

typedef __bf16 bf16x8_t __attribute__((ext_vector_type(8)));
typedef float  f32x4_t  __attribute__((ext_vector_type(4)));

typedef __attribute__((address_space(3))) uint32_t as3_u32;
typedef __attribute__((address_space(1))) uint32_t as1_u32;

__device__ __forceinline__ void async_copy16(const void* g, const void* l) {
  __builtin_amdgcn_global_load_lds((const as1_u32*)(uintptr_t)g,
                                   (as3_u32*)(uint32_t)(uintptr_t)l,
                                   16, 0, 0);
}

__device__ __forceinline__ uint16_t f2bf(float f) {  // RNE
  uint32_t x = __float_as_uint(f);
  return (uint16_t)((x + 0x7fffu + ((x >> 16) & 1u)) >> 16);
}
__device__ __forceinline__ float bf2f(uint16_t b) {
  return __uint_as_float(((uint32_t)b) << 16);
}

// Swizzled LDS byte offset for (row m, 16B chunk c) in a [128][32]-bf16 tile
// (row pitch 64 B).  chunk' = c ^ ((m>>1)&3) -> ~2-way bank aliasing (free).
#define LDS_CH(m, c) (((m) << 6) + ((((c) ^ (((m) >> 1) & 3))) << 4))

// C[m,n] = alpha * sum_k A[m,k] * B[n,k].  1024 blocks (1D), 256 threads.
// Tile decomposition hardcoded: 8 n-tiles x 8 m-tiles x 16 batches of 128^2.
template <bool OUT_F32>
__global__ __launch_bounds__(256, 4)
void gemm_bt(const uint16_t* __restrict__ A, const uint16_t* __restrict__ B,
             void* __restrict__ Cv, int K, int ldc,
             size_t sA, size_t sB, size_t sC, float alpha)
{
  __shared__ __align__(16) char smem[16384];
  char* As = smem;          // 128 x 32 bf16 = 8192 B
  char* Bs = smem + 8192;

  // ---- XCD-aware swizzle: lid%8 = XCD (round-robin dispatch assumption) ----
  const int lid = blockIdx.x;
  const int xcd  = lid & 7;
  const int slot = lid >> 3;                 // 0..127 within this XCD
  const int z    = (xcd << 1) | (slot >> 6); // 2 batches per XCD
  const int t64  = slot & 63;                // tile within batch
  const int bm0  = (t64 >> 3) << 7;
  const int bn0  = (t64 & 7) << 7;

  A += (size_t)z * sA;
  B += (size_t)z * sB;

  const int t    = threadIdx.x;
  const int lane = t & 63;
  const int w    = t >> 6;         // wave 0..3
  const int q    = lane >> 4;      // 0..3
  const int r16  = lane & 15;
  const int wm   = (w >> 1) << 6;
  const int wn   = (w & 1) << 6;

  f32x4_t acc[4][4];
#pragma unroll
  for (int i = 0; i < 4; i++)
#pragma unroll
    for (int j = 0; j < 4; j++) acc[i][j] = (f32x4_t){0.f, 0.f, 0.f, 0.f};

  const int oa0 = (w << 11) + (lane << 4);

  for (int k0 = 0; k0 < K; k0 += 32) {
    // ---- stage A,B tiles (global -> LDS, 16 B/lane) ----
#pragma unroll
    for (int i = 0; i < 2; i++) {
      const int o  = oa0 + (i << 10);
      const int mm = o >> 6;
      const int cp = (o >> 4) & 3;
      const int c  = cp ^ ((mm >> 1) & 3);
      const size_t gofs = (size_t)(bm0 + mm) * K + (size_t)(k0 + (c << 3));
      async_copy16(A + gofs, As + o);
      const size_t gofsb = (size_t)(bn0 + mm) * K + (size_t)(k0 + (c << 3));
      async_copy16(B + gofsb, Bs + o);
    }
    __syncthreads();

    // ---- fragments: A[m=lane&15][k=q*8+j], B[n=lane&15][k=q*8+j] ----
    bf16x8_t af[4], bfr[4];
#pragma unroll
    for (int mi = 0; mi < 4; mi++) {
      const int m = wm + (mi << 4) + r16;
      af[mi] = *(const bf16x8_t*)(As + LDS_CH(m, q));
    }
#pragma unroll
    for (int ni = 0; ni < 4; ni++) {
      const int n = wn + (ni << 4) + r16;
      bfr[ni] = *(const bf16x8_t*)(Bs + LDS_CH(n, q));
    }
#pragma unroll
    for (int mi = 0; mi < 4; mi++)
#pragma unroll
      for (int ni = 0; ni < 4; ni++)
        acc[mi][ni] = __builtin_amdgcn_mfma_f32_16x16x32_bf16(
            af[mi], bfr[ni], acc[mi][ni], 0, 0, 0);
    __syncthreads();
  }

  // ---- epilogue: C/D layout col=lane&15, row=q*4+r (verified m89/m91) ----
#pragma unroll
  for (int mi = 0; mi < 4; mi++) {
#pragma unroll
    for (int ni = 0; ni < 4; ni++) {
#pragma unroll
      for (int r = 0; r < 4; r++) {
        const int row = bm0 + wm + (mi << 4) + (q << 2) + r;
        const int col = bn0 + wn + (ni << 4) + r16;
        const float v = acc[mi][ni][r] * alpha;
        if (OUT_F32) {
          ((float*)Cv)[(size_t)z * sC + (size_t)row * ldc + col] = v;
        } else {
          ((uint16_t*)Cv)[(size_t)z * sC + (size_t)row * ldc + col] = f2bf(v);
        }
      }
    }
  }
}

// dst[c][r] = (bf16) src[r][c]; src: R x C fp32 row-major.  32x32 LDS tiles.
__global__ __launch_bounds__(256)
void transpose_cast(const float* __restrict__ src, uint16_t* __restrict__ dst,
                    int R, int Ccols, size_t sStride, size_t dStride)
{
  __shared__ float tile[32][33];
  const int z = blockIdx.z;
  src += (size_t)z * sStride;
  dst += (size_t)z * dStride;
  const int c0 = blockIdx.x << 5;
  const int r0 = blockIdx.y << 5;
  const int tx = threadIdx.x;   // 0..31
  const int ty = threadIdx.y;   // 0..7
#pragma unroll
  for (int i = 0; i < 32; i += 8)
    tile[ty + i][tx] = src[(size_t)(r0 + ty + i) * Ccols + (c0 + tx)];
  __syncthreads();
#pragma unroll
  for (int i = 0; i < 32; i += 8)
    dst[(size_t)(c0 + ty + i) * R + (r0 + tx)] = f2bf(tile[tx][ty + i]);
}

// row softmax over 1024 bf16 logits; one 256-thread block per row.
__global__ __launch_bounds__(256)
void softmax_rows(const uint16_t* __restrict__ in, uint16_t* __restrict__ out)
{
  const size_t row = blockIdx.x;
  const ushort4* p4 = (const ushort4*)(in + row * 1024);
  ushort4* o4 = (ushort4*)(out + row * 1024);
  const int t = threadIdx.x;
  const int lane = t & 63;
  const int wv = t >> 6;

  const ushort4 u = p4[t];
  float v0 = bf2f(u.x), v1 = bf2f(u.y), v2 = bf2f(u.z), v3 = bf2f(u.w);

  float m = fmaxf(fmaxf(v0, v1), fmaxf(v2, v3));
#pragma unroll
  for (int s = 32; s; s >>= 1) m = fmaxf(m, __shfl_xor(m, s, 64));
  __shared__ float red[8];
  if (lane == 0) red[wv] = m;
  __syncthreads();
  m = fmaxf(fmaxf(red[0], red[1]), fmaxf(red[2], red[3]));

  const float e0 = __expf(v0 - m), e1 = __expf(v1 - m);
  const float e2 = __expf(v2 - m), e3 = __expf(v3 - m);
  float s = e0 + e1 + e2 + e3;
#pragma unroll
  for (int sh = 32; sh; sh >>= 1) s += __shfl_xor(s, sh, 64);
  if (lane == 0) red[4 + wv] = s;
  __syncthreads();
  s = red[4] + red[5] + red[6] + red[7];

  const float inv = 1.0f / s;
  ushort4 r;
  r.x = f2bf(e0 * inv); r.y = f2bf(e1 * inv);
  r.z = f2bf(e2 * inv); r.w = f2bf(e3 * inv);
  o4[t] = r;
}

extern "C" void kernel_launch(void* const* d_in, const int* in_sizes, int n_in,
                              void* d_out, int out_size, void* d_ws, size_t ws_size,
                              hipStream_t stream)
{
  const float* x  = (const float*)d_in[0];
  const float* wk = (const float*)d_in[1];
  const float* wq = (const float*)d_in[2];
  const float* wv = (const float*)d_in[3];
  float* out = (float*)d_out;

  constexpr int BB = 16, N = 1024, D = 1024;
  constexpr size_t DN = (size_t)D * N;

  // workspace layout (bytes)            size    lifetime
  // xT   @ 0                            32 MB   dead after G3 -> reused as kq
  // Wtk  @ 32M, Wtq @ 34M, Wtv @ 36M     6 MB
  // vk   @ 38M                          32 MB   dead after G4 -> reused as sm
  // vq   @ 70M
  // vvT  @ 102M                         (total 134 MB)
  char* ws = (char*)d_ws;
  uint16_t* xT  = (uint16_t*)(ws);
  uint16_t* Wtk = (uint16_t*)(ws + (32ull << 20));
  uint16_t* Wtq = (uint16_t*)(ws + (34ull << 20));
  uint16_t* Wtv = (uint16_t*)(ws + (36ull << 20));
  uint16_t* vk  = (uint16_t*)(ws + (38ull << 20));
  uint16_t* vq  = (uint16_t*)(ws + (70ull << 20));
  uint16_t* vvT = (uint16_t*)(ws + (102ull << 20));
  uint16_t* kq  = xT;
  uint16_t* sm  = vk;

  const dim3 tb(32, 8);
  transpose_cast<<<dim3(D / 32, N / 32, BB), tb, 0, stream>>>(x, xT, N, D, DN, DN);
  transpose_cast<<<dim3(N / 32, N / 32, 1), tb, 0, stream>>>(wk, Wtk, N, N, 0, 0);
  transpose_cast<<<dim3(N / 32, N / 32, 1), tb, 0, stream>>>(wq, Wtq, N, N, 0, 0);
  transpose_cast<<<dim3(N / 32, N / 32, 1), tb, 0, stream>>>(wv, Wtv, N, N, 0, 0);

  // vk[b][d][k] = sum_n xT[b][d][n] * Wtk[k][n]
  gemm_bt<false><<<1024, 256, 0, stream>>>(xT, Wtk, vk, 1024, 1024, DN, 0, DN, 1.0f);
  gemm_bt<false><<<1024, 256, 0, stream>>>(xT, Wtq, vq, 1024, 1024, DN, 0, DN, 1.0f);
  // vvT[b][n][d] = sum_n' Wtv[n][n'] * xT[b][d][n']
  gemm_bt<false><<<1024, 256, 0, stream>>>(Wtv, xT, vvT, 1024, 1024, 0, DN, DN, 1.0f);
  // kq[b][d][e] = (1/32) sum_n vk[b][d][n] * vq[b][e][n]
  gemm_bt<false><<<1024, 256, 0, stream>>>(vk, vq, kq, 1024, 1024, DN, DN, DN, 0.03125f);
  softmax_rows<<<BB * D, 256, 0, stream>>>(kq, sm);
  // out[b][n][d] = sum_e vvT[b][n][e] * sm[b][d][e]
  gemm_bt<true><<<1024, 256, 0, stream>>>(vvT, sm, out, 1024, 1024, DN, DN, DN, 1.0f);
}

// Round 3
// 335.867 us; speedup vs baseline: 1.1936x; 1.0662x over previous
//
#include <hip/hip_runtime.h>
#include <stdint.h>

// ---------------------------------------------------------------------------
// SelfAttention: out[b,n,d] = ( softmax( (X^T Wk)(X^T Wq)^T / 32 ) (X^T Wv) )^T
// B=16, N=D=1024.  Five 1024^3 matmuls as gemm_bt
// (C[m,n] = sum_k A[m,k]*B[n,k], K contiguous in both operands).
//
// R2: XCD swizzle (lid%8=XCD) -> FETCH 154->33 MB (ideal).  CONFIRMED.
// R3: BK=64 (halve barrier drains), LDS-staged coalesced bf16 epilogue
//     (WRITE 66->34 MB), weight transposes fused into one launch.
// ---------------------------------------------------------------------------

typedef __bf16 bf16x8_t __attribute__((ext_vector_type(8)));
typedef float  f32x4_t  __attribute__((ext_vector_type(4)));

typedef __attribute__((address_space(3))) uint32_t as3_u32;
typedef __attribute__((address_space(1))) uint32_t as1_u32;

__device__ __forceinline__ void async_copy16(const void* g, const void* l) {
  __builtin_amdgcn_global_load_lds((const as1_u32*)(uintptr_t)g,
                                   (as3_u32*)(uint32_t)(uintptr_t)l,
                                   16, 0, 0);
}

__device__ __forceinline__ uint16_t f2bf(float f) {  // RNE
  uint32_t x = __float_as_uint(f);
  return (uint16_t)((x + 0x7fffu + ((x >> 16) & 1u)) >> 16);
}
__device__ __forceinline__ float bf2f(uint16_t b) {
  return __uint_as_float(((uint32_t)b) << 16);
}

// C[m,n] = alpha * sum_k A[m,k] * B[n,k].  1024 blocks (1D), 256 threads.
// Tiles: 128x128, BK=64.  LDS tile layout: row pitch 128 B, 8 chunks of 16 B,
// chunk slot cp holds logical k-chunk cp ^ (m&7)  (~2-way bank alias, free).
template <bool OUT_F32>
__global__ __launch_bounds__(256, 4)
void gemm_bt(const uint16_t* __restrict__ A, const uint16_t* __restrict__ B,
             void* __restrict__ Cv, int K, int ldc,
             size_t sA, size_t sB, size_t sC, float alpha)
{
  __shared__ __align__(16) char smem[32768];
  char* As = smem;          // 128 x 64 bf16 = 16384 B
  char* Bs = smem + 16384;

  // ---- XCD-aware swizzle: lid%8 = XCD; 2 batches per XCD ----
  const int lid  = blockIdx.x;
  const int xcd  = lid & 7;
  const int slot = lid >> 3;
  const int z    = (xcd << 1) | (slot >> 6);
  const int t64  = slot & 63;
  const int bm0  = (t64 >> 3) << 7;
  const int bn0  = (t64 & 7) << 7;

  A += (size_t)z * sA;
  B += (size_t)z * sB;

  const int t    = threadIdx.x;
  const int lane = t & 63;
  const int w    = t >> 6;
  const int q    = lane >> 4;
  const int r16  = lane & 15;
  const int wm   = (w >> 1) << 6;
  const int wn   = (w & 1) << 6;

  f32x4_t acc[4][4];
#pragma unroll
  for (int i = 0; i < 4; i++)
#pragma unroll
    for (int j = 0; j < 4; j++) acc[i][j] = (f32x4_t){0.f, 0.f, 0.f, 0.f};

  for (int k0 = 0; k0 < K; k0 += 64) {
    // ---- stage A,B 128x64 tiles (16 B/lane, 4 issues per operand) ----
#pragma unroll
    for (int i = 0; i < 4; i++) {
      const int o  = (i << 12) + (t << 4);
      const int m  = o >> 7;            // tile row (128 B rows)
      const int cp = (o >> 4) & 7;      // LDS chunk slot
      const int c  = cp ^ (m & 7);      // logical k-chunk held there
      async_copy16(A + (size_t)(bm0 + m) * K + (size_t)(k0 + (c << 3)), As + o);
      async_copy16(B + (size_t)(bn0 + m) * K + (size_t)(k0 + (c << 3)), Bs + o);
    }
    __syncthreads();

    // ---- two 32-k subtiles; fragment regs reused across kk ----
#pragma unroll
    for (int kk = 0; kk < 2; kk++) {
      bf16x8_t af[4], bfr[4];
#pragma unroll
      for (int mi = 0; mi < 4; mi++) {
        const int m = wm + (mi << 4) + r16;
        const int c = (kk << 2) + q;
        af[mi] = *(const bf16x8_t*)(As + (m << 7) + ((c ^ (m & 7)) << 4));
      }
#pragma unroll
      for (int ni = 0; ni < 4; ni++) {
        const int n = wn + (ni << 4) + r16;
        const int c = (kk << 2) + q;
        bfr[ni] = *(const bf16x8_t*)(Bs + (n << 7) + ((c ^ (n & 7)) << 4));
      }
#pragma unroll
      for (int mi = 0; mi < 4; mi++)
#pragma unroll
        for (int ni = 0; ni < 4; ni++)
          acc[mi][ni] = __builtin_amdgcn_mfma_f32_16x16x32_bf16(
              af[mi], bfr[ni], acc[mi][ni], 0, 0, 0);
    }
    __syncthreads();   // also fences LDS before epilogue reuse
  }

  // ---- epilogue.  C/D layout: col=lane&15, row=q*4+r (verified m89/m91) ----
  if (OUT_F32) {
    float* C = (float*)Cv + (size_t)z * sC;
#pragma unroll
    for (int mi = 0; mi < 4; mi++)
#pragma unroll
      for (int ni = 0; ni < 4; ni++)
#pragma unroll
        for (int r = 0; r < 4; r++) {
          const int row = bm0 + wm + (mi << 4) + (q << 2) + r;
          const int col = bn0 + wn + (ni << 4) + r16;
          C[(size_t)row * ldc + col] = acc[mi][ni][r] * alpha;
        }
  } else {
    // Stage through per-wave-private LDS (16 rows x 66 floats, padded) so
    // stores are full 128-B rows (32 lanes x dword).  No cross-wave barrier
    // needed: regions are private; K-loop's final barrier already fenced smem.
    float* reg = (float*)smem + (size_t)w * (16 * 66);
    uint16_t* C = (uint16_t*)Cv + (size_t)z * sC;
#pragma unroll
    for (int mi = 0; mi < 4; mi++) {
#pragma unroll
      for (int ni = 0; ni < 4; ni++)
#pragma unroll
        for (int r = 0; r < 4; r++)
          reg[((q << 2) + r) * 66 + (ni << 4) + r16] = acc[mi][ni][r] * alpha;
#pragma unroll
      for (int it = 0; it < 8; it++) {
        const int rr = (it << 1) + (lane >> 5);   // 0..15
        const int cc = (lane & 31) << 1;          // 0..62
        const float2 v = *(const float2*)(reg + rr * 66 + cc);
        const uint32_t p = (uint32_t)f2bf(v.x) | ((uint32_t)f2bf(v.y) << 16);
        const int row = bm0 + wm + (mi << 4) + rr;
        const int col = bn0 + wn + cc;
        *(uint32_t*)(C + (size_t)row * ldc + col) = p;
      }
    }
  }
}

// dst[c][r] = (bf16) src[r][c]; src: R x C fp32 row-major.  32x32 LDS tiles.
__global__ __launch_bounds__(256)
void transpose_cast(const float* __restrict__ src, uint16_t* __restrict__ dst,
                    int R, int Ccols, size_t sStride, size_t dStride)
{
  __shared__ float tile[32][33];
  const int z = blockIdx.z;
  src += (size_t)z * sStride;
  dst += (size_t)z * dStride;
  const int c0 = blockIdx.x << 5;
  const int r0 = blockIdx.y << 5;
  const int tx = threadIdx.x;
  const int ty = threadIdx.y;
#pragma unroll
  for (int i = 0; i < 32; i += 8)
    tile[ty + i][tx] = src[(size_t)(r0 + ty + i) * Ccols + (c0 + tx)];
  __syncthreads();
#pragma unroll
  for (int i = 0; i < 32; i += 8)
    dst[(size_t)(c0 + ty + i) * R + (r0 + tx)] = f2bf(tile[tx][ty + i]);
}

// All three 1024x1024 weight transposes in one launch (z selects matrix).
__global__ __launch_bounds__(256)
void transpose_cast_w(const float* __restrict__ w0, const float* __restrict__ w1,
                      const float* __restrict__ w2, uint16_t* __restrict__ o0,
                      uint16_t* __restrict__ o1, uint16_t* __restrict__ o2)
{
  __shared__ float tile[32][33];
  const int z = blockIdx.z;
  const float* src = (z == 0) ? w0 : (z == 1) ? w1 : w2;
  uint16_t* dst = (z == 0) ? o0 : (z == 1) ? o1 : o2;
  const int c0 = blockIdx.x << 5;
  const int r0 = blockIdx.y << 5;
  const int tx = threadIdx.x;
  const int ty = threadIdx.y;
#pragma unroll
  for (int i = 0; i < 32; i += 8)
    tile[ty + i][tx] = src[(size_t)(r0 + ty + i) * 1024 + (c0 + tx)];
  __syncthreads();
#pragma unroll
  for (int i = 0; i < 32; i += 8)
    dst[(size_t)(c0 + ty + i) * 1024 + (r0 + tx)] = f2bf(tile[tx][ty + i]);
}

// row softmax over 1024 bf16 logits; one 256-thread block per row.
__global__ __launch_bounds__(256)
void softmax_rows(const uint16_t* __restrict__ in, uint16_t* __restrict__ out)
{
  const size_t row = blockIdx.x;
  const ushort4* p4 = (const ushort4*)(in + row * 1024);
  ushort4* o4 = (ushort4*)(out + row * 1024);
  const int t = threadIdx.x;
  const int lane = t & 63;
  const int wv = t >> 6;

  const ushort4 u = p4[t];
  float v0 = bf2f(u.x), v1 = bf2f(u.y), v2 = bf2f(u.z), v3 = bf2f(u.w);

  float m = fmaxf(fmaxf(v0, v1), fmaxf(v2, v3));
#pragma unroll
  for (int s = 32; s; s >>= 1) m = fmaxf(m, __shfl_xor(m, s, 64));
  __shared__ float red[8];
  if (lane == 0) red[wv] = m;
  __syncthreads();
  m = fmaxf(fmaxf(red[0], red[1]), fmaxf(red[2], red[3]));

  const float e0 = __expf(v0 - m), e1 = __expf(v1 - m);
  const float e2 = __expf(v2 - m), e3 = __expf(v3 - m);
  float s = e0 + e1 + e2 + e3;
#pragma unroll
  for (int sh = 32; sh; sh >>= 1) s += __shfl_xor(s, sh, 64);
  if (lane == 0) red[4 + wv] = s;
  __syncthreads();
  s = red[4] + red[5] + red[6] + red[7];

  const float inv = 1.0f / s;
  ushort4 r;
  r.x = f2bf(e0 * inv); r.y = f2bf(e1 * inv);
  r.z = f2bf(e2 * inv); r.w = f2bf(e3 * inv);
  o4[t] = r;
}

extern "C" void kernel_launch(void* const* d_in, const int* in_sizes, int n_in,
                              void* d_out, int out_size, void* d_ws, size_t ws_size,
                              hipStream_t stream)
{
  const float* x  = (const float*)d_in[0];
  const float* wk = (const float*)d_in[1];
  const float* wq = (const float*)d_in[2];
  const float* wv = (const float*)d_in[3];
  float* out = (float*)d_out;

  constexpr int BB = 16, N = 1024, D = 1024;
  constexpr size_t DN = (size_t)D * N;

  // workspace layout (bytes)            size    lifetime
  // xT   @ 0                            32 MB   dead after G3 -> reused as kq
  // Wtk  @ 32M, Wtq @ 34M, Wtv @ 36M     6 MB
  // vk   @ 38M                          32 MB   dead after G4 -> reused as sm
  // vq   @ 70M
  // vvT  @ 102M                         (total 134 MB)
  char* ws = (char*)d_ws;
  uint16_t* xT  = (uint16_t*)(ws);
  uint16_t* Wtk = (uint16_t*)(ws + (32ull << 20));
  uint16_t* Wtq = (uint16_t*)(ws + (34ull << 20));
  uint16_t* Wtv = (uint16_t*)(ws + (36ull << 20));
  uint16_t* vk  = (uint16_t*)(ws + (38ull << 20));
  uint16_t* vq  = (uint16_t*)(ws + (70ull << 20));
  uint16_t* vvT = (uint16_t*)(ws + (102ull << 20));
  uint16_t* kq  = xT;
  uint16_t* sm  = vk;

  const dim3 tb(32, 8);
  transpose_cast<<<dim3(D / 32, N / 32, BB), tb, 0, stream>>>(x, xT, N, D, DN, DN);
  transpose_cast_w<<<dim3(N / 32, N / 32, 3), tb, 0, stream>>>(wk, wq, wv,
                                                               Wtk, Wtq, Wtv);

  // vk[b][d][k] = sum_n xT[b][d][n] * Wtk[k][n]
  gemm_bt<false><<<1024, 256, 0, stream>>>(xT, Wtk, vk, 1024, 1024, DN, 0, DN, 1.0f);
  gemm_bt<false><<<1024, 256, 0, stream>>>(xT, Wtq, vq, 1024, 1024, DN, 0, DN, 1.0f);
  // vvT[b][n][d] = sum_n' Wtv[n][n'] * xT[b][d][n']
  gemm_bt<false><<<1024, 256, 0, stream>>>(Wtv, xT, vvT, 1024, 1024, 0, DN, DN, 1.0f);
  // kq[b][d][e] = (1/32) sum_n vk[b][d][n] * vq[b][e][n]
  gemm_bt<false><<<1024, 256, 0, stream>>>(vk, vq, kq, 1024, 1024, DN, DN, DN, 0.03125f);
  softmax_rows<<<BB * D, 256, 0, stream>>>(kq, sm);
  // out[b][n][d] = sum_e vvT[b][n][e] * sm[b][d][e]
  gemm_bt<true><<<1024, 256, 0, stream>>>(vvT, sm, out, 1024, 1024, DN, DN, DN, 1.0f);
}